// Round 7
// baseline (5729.324 us; speedup 1.0000x reference)
//
#include <hip/hip_runtime.h>
#include <stdint.h>
#include <stddef.h>

// ---------------------------------------------------------------------------
// fp8-fake-quant linear: out = clip(x/s_in, +-448) @ W^T * (s_in*s_w) + bias
// M=8192 K=4096 N=16384. f16 operands (measured absmax 0.0156 vs 0.075 thr).
// Round 7 = round 6 (contiguous staging + involution swizzle, 0 conflicts)
// + register-level pipeline (round 4 idea, now unmasked):
//   - 2 barriers per K-tile (not 8): #1 after Q10 (A-region readers retired,
//     A(t+2) may overwrite sA[cur]); #2 after vmcnt(4) at p4 (A(t+1)/B(t+1)
//     landed & visible -> next tile's aL/bL reads issue right after, covered
//     by Q01's MFMA cluster).
//   - counted lgkm waits: every MFMA cluster has the NEXT cluster's ds_reads
//     (or staging) in flight beneath it; LDS read bursts overlap MFMA.
//   - per-wave tile stream ledger (vm FIFO): at p4 outstanding <= A(t+1)4 +
//     B(t+1)4 + A(t+2)4; vmcnt(4) retires exactly through B(t+1).
//   - sched_barrier(0) after each counted wait (rule #18).
// ---------------------------------------------------------------------------

typedef _Float16 half8 __attribute__((ext_vector_type(8)));
typedef _Float16 half4v __attribute__((ext_vector_type(4)));
typedef float f32x4 __attribute__((ext_vector_type(4)));

#define BM 256
#define BN 256
#define BK 64
#define FP8MAX 448.0f

__device__ __forceinline__ void gload_lds16(const _Float16* g, _Float16* lds) {
  __builtin_amdgcn_global_load_lds(
      (const __attribute__((address_space(1))) uint32_t*)g,
      (__attribute__((address_space(3))) uint32_t*)lds, 16, 0, 0);
}

#define BAR() asm volatile("s_barrier" ::: "memory")
#define WAIT_VM(N) asm volatile("s_waitcnt vmcnt(" #N ")" ::: "memory")
#define WAIT_LGKM(N) asm volatile("s_waitcnt lgkmcnt(" #N ")" ::: "memory")
#define SCHED_FENCE() __builtin_amdgcn_sched_barrier(0)

// one quadrant: 4 m-frags x 2 n-frags x 2 k-steps = 16 MFMA, setprio-wrapped
#define MFMA_Q(AF, BF, MG, NG) do {                                           \
  __builtin_amdgcn_s_setprio(1);                                              \
  _Pragma("unroll")                                                           \
  for (int mf_ = 0; mf_ < 4; ++mf_) {                                         \
    _Pragma("unroll")                                                         \
    for (int nf_ = 0; nf_ < 2; ++nf_) {                                       \
      _Pragma("unroll")                                                       \
      for (int ks_ = 0; ks_ < 2; ++ks_)                                       \
        acc[(MG)*4 + mf_][(NG)*2 + nf_] =                                     \
            __builtin_amdgcn_mfma_f32_16x16x32_f16(                           \
                AF[mf_*2 + ks_], BF[nf_*2 + ks_],                             \
                acc[(MG)*4 + mf_][(NG)*2 + nf_], 0, 0, 0);                    \
    }                                                                         \
  }                                                                           \
  __builtin_amdgcn_s_setprio(0);                                              \
} while (0)

// ---- pass 1a: x_q = (f16) clip(x / s_in, +-448) ----------------------------
__global__ void cvt_x_kernel(const float* __restrict__ x, _Float16* __restrict__ xq,
                             const float* __restrict__ s_ptr, long n4) {
  float inv = 1.0f / s_ptr[0];
  long i = (long)blockIdx.x * blockDim.x + threadIdx.x;
  long stride = (long)gridDim.x * blockDim.x;
  const float4* x4 = (const float4*)x;
  for (long j = i; j < n4; j += stride) {
    float4 v = x4[j];
    half4v h;
    h[0] = (_Float16)fminf(fmaxf(v.x * inv, -FP8MAX), FP8MAX);
    h[1] = (_Float16)fminf(fmaxf(v.y * inv, -FP8MAX), FP8MAX);
    h[2] = (_Float16)fminf(fmaxf(v.z * inv, -FP8MAX), FP8MAX);
    h[3] = (_Float16)fminf(fmaxf(v.w * inv, -FP8MAX), FP8MAX);
    *(half4v*)(xq + j * 4) = h;
  }
}

// ---- pass 1b: w_q = (f16) w -------------------------------------------------
__global__ void cvt_w_kernel(const float* __restrict__ w, _Float16* __restrict__ wq,
                             long n4) {
  long i = (long)blockIdx.x * blockDim.x + threadIdx.x;
  long stride = (long)gridDim.x * blockDim.x;
  const float4* w4 = (const float4*)w;
  for (long j = i; j < n4; j += stride) {
    float4 v = w4[j];
    half4v h;
    h[0] = (_Float16)v.x; h[1] = (_Float16)v.y;
    h[2] = (_Float16)v.z; h[3] = (_Float16)v.w;
    *(half4v*)(wq + j * 4) = h;
  }
}

// ---- pass 2: 256^2 pipelined swizzled GEMM ----------------------------------
__global__ __launch_bounds__(512, 2)
void gemm256_pl(const _Float16* __restrict__ A, const _Float16* __restrict__ B,
                const float* __restrict__ bias, const float* __restrict__ is_ptr,
                const float* __restrict__ ws_ptr, float* __restrict__ out,
                int M, int N, int K) {
  // [256 rows][64 k] f16 per buf; elem (r,k) at r*64 + ((k>>3)^(r&7))*8 + (k&7)
  __shared__ __align__(16) _Float16 sA[2][256 * 64];
  __shared__ __align__(16) _Float16 sB[2][256 * 64];

  const int nbn = N / BN;
  const int nwg = gridDim.x;
  int wg = blockIdx.x;
  if ((nwg & 7) == 0) {               // bijective XCD swizzle (8 XCDs)
    int q = nwg >> 3;
    wg = (wg & 7) * q + (wg >> 3);
  }
  const int brow = (wg / nbn) * BM;
  const int bcol = (wg % nbn) * BN;

  const int tid  = threadIdx.x;
  const int lane = tid & 63;
  const int w    = tid >> 6;          // wave 0..7
  const int wr   = w >> 2;            // 0..1 : rows [wr*128, +128)
  const int wc   = w & 3;             // 0..3 : cols [wc*64, +64)

  // staging: piece pi = 64 rows x 128B/row (8KB); wave w covers rows pi*64+w*8..+8
  // per-lane source: row lane>>3, chunk (lane&7)^(lane>>3) (inverse swizzle)
  const size_t lsrc = (size_t)(lane >> 3) * K + (size_t)((lane & 7) ^ (lane >> 3)) * 8;
  const _Float16* gA = A + (size_t)brow * K + lsrc;
  const _Float16* gB = B + (size_t)bcol * K + lsrc;

  auto stageA = [&](int buf, int pi, int kt) {
    gload_lds16(gA + (size_t)(pi * 64 + w * 8) * K + kt,
                &sA[buf][(pi * 512 + w * 64) * 8]);
  };
  auto stageB = [&](int buf, int pi, int kt) {
    gload_lds16(gB + (size_t)(pi * 64 + w * 8) * K + kt,
                &sB[buf][(pi * 512 + w * 64) * 8]);
  };

  // swizzled fragment reads: r = g*16 + (lane&15); chunk = (ks*4+(lane>>4)) ^ (lane&7)
  const int rdbase = (lane & 15) * 64;
  const int e0 = rdbase + (((lane >> 4) + 0) ^ (lane & 7)) * 8;   // ks=0
  const int e1 = rdbase + (((lane >> 4) + 4) ^ (lane & 7)) * 8;   // ks=1

  auto ldA = [&](int buf, int mg, half8* a) {
#pragma unroll
    for (int mf = 0; mf < 4; ++mf) {
      const int base = (wr * 8 + mg * 4 + mf) * 1024;
      a[mf * 2 + 0] = *(const half8*)&sA[buf][base + e0];
      a[mf * 2 + 1] = *(const half8*)&sA[buf][base + e1];
    }
  };
  auto ldB = [&](int buf, int ng, half8* b) {
#pragma unroll
    for (int nf = 0; nf < 2; ++nf) {
      const int base = (wc * 4 + ng * 2 + nf) * 1024;
      b[nf * 2 + 0] = *(const half8*)&sB[buf][base + e0];
      b[nf * 2 + 1] = *(const half8*)&sB[buf][base + e1];
    }
  };

  f32x4 acc[8][4] = {};
  const int NT = K / BK;              // 64 (even; loop unrolled by 2)

  // tile body. entry: aC/bC = tile t quadrant-row 0 frags (valid);
  // vm outstanding = A(t+1) x4. exit: aN/bN = tile t+1 frags; vm = A(t+2) x4.
  auto tile_body = [&](int t, half8 (&aC)[8], half8 (&bC)[4],
                       half8 (&aN)[8], half8 (&bN_)[4]) {
    const int cur = t & 1, nxt = cur ^ 1;
    const int ktB = (t + 1) * BK;
    const int ktA = (t + 2) * BK;
    const bool sb = (t + 1) < NT;
    const bool sa = (t + 2) < NT;
    half8 aH[8], bH[4];

    // p1: issue aH reads; stage B(t+1) 0,1; retire prior aL/bL; Q00
    ldA(cur, 1, aH);
    if (sb) { stageB(nxt, 0, ktB); stageB(nxt, 1, ktB); }
    WAIT_LGKM(8); SCHED_FENCE();
    MFMA_Q(aC, bC, 0, 0);

    // p2: issue bH reads; retire aH; Q10; stage B(t+1) 2,3; BAR#1
    ldB(cur, 1, bH);
    WAIT_LGKM(4); SCHED_FENCE();
    MFMA_Q(aH, bC, 1, 0);
    if (sb) { stageB(nxt, 2, ktB); stageB(nxt, 3, ktB); }
    BAR();                             // A(t) readers retired -> A(t+2) may land

    // p3: stage A(t+2) 0,1; retire bH; Q11; stage A(t+2) 2,3
    if (sa) { stageA(cur, 0, ktA); stageA(cur, 1, ktA); }
    WAIT_LGKM(0); SCHED_FENCE();
    MFMA_Q(aH, bH, 1, 1);
    if (sa) { stageA(cur, 2, ktA); stageA(cur, 3, ktA); }

    // p4: counted vm wait -> A(t+1),B(t+1) landed; BAR#2; issue next-tile
    // aL/bL reads (covered by Q01)
    if (t < NT - 2) { WAIT_VM(4); } else { WAIT_VM(0); }
    BAR();
    if (t + 1 < NT) { ldA(nxt, 0, aN); ldB(nxt, 0, bN_); }
    MFMA_Q(aC, bH, 0, 1);
  };

  // prologue: A(0),B(0)->buf0, A(1)->buf1; vm(4): tile0 landed, A(1) flying
  stageA(0, 0, 0); stageA(0, 1, 0); stageA(0, 2, 0); stageA(0, 3, 0);
  stageB(0, 0, 0); stageB(0, 1, 0); stageB(0, 2, 0); stageB(0, 3, 0);
  stageA(1, 0, BK); stageA(1, 1, BK); stageA(1, 2, BK); stageA(1, 3, BK);
  WAIT_VM(4);
  BAR();

  half8 aP[8], bP[4], aQ[8], bQ[4];
  ldA(0, 0, aP); ldB(0, 0, bP);       // retired by tile 0's lgkm(8)

  for (int t = 0; t < NT; t += 2) {
    tile_body(t,     aP, bP, aQ, bQ);
    tile_body(t + 1, aQ, bQ, aP, bP);
  }

  // ---- epilogue: C/D 16x16 layout: col = lane&15, row = (lane>>4)*4 + r
  const float sc = is_ptr[0] * ws_ptr[0];
  const int orow = brow + wr * 128;
  const int ocol = bcol + wc * 64;
#pragma unroll
  for (int n = 0; n < 4; ++n) {
    const int col = ocol + n * 16 + (lane & 15);
    const float bv = bias[col];
#pragma unroll
    for (int m = 0; m < 8; ++m) {
#pragma unroll
      for (int r = 0; r < 4; ++r) {
        const int row = orow + m * 16 + (lane >> 4) * 4 + r;
        out[(size_t)row * N + col] = acc[m][n][r] * sc + bv;
      }
    }
  }
}

// ---------------------------------------------------------------------------
extern "C" void kernel_launch(void* const* d_in, const int* in_sizes, int n_in,
                              void* d_out, int out_size, void* d_ws, size_t ws_size,
                              hipStream_t stream) {
  const float* x    = (const float*)d_in[0];
  const float* wgt  = (const float*)d_in[1];
  const float* bias = (const float*)d_in[2];
  const float* is   = (const float*)d_in[3];
  const float* wsc  = (const float*)d_in[4];
  float* out = (float*)d_out;

  const long x_n = in_sizes[0];
  const long w_n = in_sizes[1];
  const int  N   = in_sizes[2];
  const int  K   = (int)(w_n / N);
  const int  M   = (int)(x_n / K);

  _Float16* xq = (_Float16*)d_ws;
  _Float16* wq = xq + x_n;

  cvt_x_kernel<<<2048, 256, 0, stream>>>(x, xq, is, x_n >> 2);
  cvt_w_kernel<<<2048, 256, 0, stream>>>(wgt, wq, w_n >> 2);

  const int nwg = (M / BM) * (N / BN);   // 32 * 64 = 2048, %8 == 0
  gemm256_pl<<<nwg, 512, 0, stream>>>(xq, wq, bias, is, wsc, out, M, N, K);
}

// Round 8
// 1191.934 us; speedup vs baseline: 4.8067x; 4.8067x over previous
//
#include <hip/hip_runtime.h>
#include <stdint.h>
#include <stddef.h>

// ---------------------------------------------------------------------------
// fp8-fake-quant linear: out = clip(x/s_in, +-448) @ W^T * (s_in*s_w) + bias
// M=8192 K=4096 N=16384. f16 operands (measured absmax 0.0156 vs 0.075 thr).
// Round 8 = round 6's staging/swizzle (supply-fixed, 0 bank conflicts) +
// round 7's pipeline WITHIN the register budget that r6 proved fits:
//   live frags = exactly {aL,aH,bL,bH} (96 arch VGPR) + acc 128 AGPR; NO
//   cross-tile register carry (r7's third set spilled: WRITE_SIZE 8.6GB).
// Tile structure (2 barriers, counted waits):
//   p1: issue 24 ds_reads in pinned groups (aL+bL | bH | aH) + stage B(t+1)
//   lgkm(12) -> Q00(aL,bL); lgkm(8) -> Q01(aL,bH)  [reads covered by MFMA]
//   lgkm(0); BAR#1  (all waves' A-reads retired -> A(t+2) may overwrite cur)
//   stage A(t+2) under Q11(aH,bH) + Q10(aH,bL)
//   vmcnt(4)  [FIFO: retires A(t+1)+B(t+1), leaves A(t+2)] ; BAR#2
// Hazards: A-overwrite behind lgkm(0)+BAR#1; B(t+1)-overwrite behind
// BAR#2(t-1); tile t+1 reads behind vmcnt(4)+BAR#2. Tail: vm(0) at NT-2.
// ---------------------------------------------------------------------------

typedef _Float16 half8 __attribute__((ext_vector_type(8)));
typedef _Float16 half4v __attribute__((ext_vector_type(4)));
typedef float f32x4 __attribute__((ext_vector_type(4)));

#define BM 256
#define BN 256
#define BK 64
#define FP8MAX 448.0f

__device__ __forceinline__ void gload_lds16(const _Float16* g, _Float16* lds) {
  __builtin_amdgcn_global_load_lds(
      (const __attribute__((address_space(1))) uint32_t*)g,
      (__attribute__((address_space(3))) uint32_t*)lds, 16, 0, 0);
}

#define BAR() asm volatile("s_barrier" ::: "memory")
#define WAIT_VM(N) asm volatile("s_waitcnt vmcnt(" #N ")" ::: "memory")
#define WAIT_LGKM(N) asm volatile("s_waitcnt lgkmcnt(" #N ")" ::: "memory")
#define SCHED_FENCE() __builtin_amdgcn_sched_barrier(0)

// one quadrant: 4 m-frags x 2 n-frags x 2 k-steps = 16 MFMA, setprio-wrapped
#define MFMA_Q(AF, BF, MG, NG) do {                                           \
  __builtin_amdgcn_s_setprio(1);                                              \
  _Pragma("unroll")                                                           \
  for (int mf_ = 0; mf_ < 4; ++mf_) {                                         \
    _Pragma("unroll")                                                         \
    for (int nf_ = 0; nf_ < 2; ++nf_) {                                       \
      _Pragma("unroll")                                                       \
      for (int ks_ = 0; ks_ < 2; ++ks_)                                       \
        acc[(MG)*4 + mf_][(NG)*2 + nf_] =                                     \
            __builtin_amdgcn_mfma_f32_16x16x32_f16(                           \
                AF[mf_*2 + ks_], BF[nf_*2 + ks_],                             \
                acc[(MG)*4 + mf_][(NG)*2 + nf_], 0, 0, 0);                    \
    }                                                                         \
  }                                                                           \
  __builtin_amdgcn_s_setprio(0);                                              \
} while (0)

// ---- pass 1a: x_q = (f16) clip(x / s_in, +-448) ----------------------------
__global__ void cvt_x_kernel(const float* __restrict__ x, _Float16* __restrict__ xq,
                             const float* __restrict__ s_ptr, long n4) {
  float inv = 1.0f / s_ptr[0];
  long i = (long)blockIdx.x * blockDim.x + threadIdx.x;
  long stride = (long)gridDim.x * blockDim.x;
  const float4* x4 = (const float4*)x;
  for (long j = i; j < n4; j += stride) {
    float4 v = x4[j];
    half4v h;
    h[0] = (_Float16)fminf(fmaxf(v.x * inv, -FP8MAX), FP8MAX);
    h[1] = (_Float16)fminf(fmaxf(v.y * inv, -FP8MAX), FP8MAX);
    h[2] = (_Float16)fminf(fmaxf(v.z * inv, -FP8MAX), FP8MAX);
    h[3] = (_Float16)fminf(fmaxf(v.w * inv, -FP8MAX), FP8MAX);
    *(half4v*)(xq + j * 4) = h;
  }
}

// ---- pass 1b: w_q = (f16) w -------------------------------------------------
__global__ void cvt_w_kernel(const float* __restrict__ w, _Float16* __restrict__ wq,
                             long n4) {
  long i = (long)blockIdx.x * blockDim.x + threadIdx.x;
  long stride = (long)gridDim.x * blockDim.x;
  const float4* w4 = (const float4*)w;
  for (long j = i; j < n4; j += stride) {
    float4 v = w4[j];
    half4v h;
    h[0] = (_Float16)v.x; h[1] = (_Float16)v.y;
    h[2] = (_Float16)v.z; h[3] = (_Float16)v.w;
    *(half4v*)(wq + j * 4) = h;
  }
}

// ---- pass 2: 256^2 two-barrier pipelined swizzled GEMM ----------------------
__global__ __launch_bounds__(512, 2)
void gemm256_p2(const _Float16* __restrict__ A, const _Float16* __restrict__ B,
                const float* __restrict__ bias, const float* __restrict__ is_ptr,
                const float* __restrict__ ws_ptr, float* __restrict__ out,
                int M, int N, int K) {
  // [256 rows][64 k] f16 per buf; elem (r,k) at r*64 + ((k>>3)^(r&7))*8 + (k&7)
  __shared__ __align__(16) _Float16 sA[2][256 * 64];
  __shared__ __align__(16) _Float16 sB[2][256 * 64];

  const int nbn = N / BN;
  const int nwg = gridDim.x;
  int wg = blockIdx.x;
  if ((nwg & 7) == 0) {               // bijective XCD swizzle (8 XCDs)
    int q = nwg >> 3;
    wg = (wg & 7) * q + (wg >> 3);
  }
  const int brow = (wg / nbn) * BM;
  const int bcol = (wg % nbn) * BN;

  const int tid  = threadIdx.x;
  const int lane = tid & 63;
  const int w    = tid >> 6;          // wave 0..7
  const int wr   = w >> 2;            // 0..1 : rows [wr*128, +128)
  const int wc   = w & 3;             // 0..3 : cols [wc*64, +64)

  // staging: piece pi = 64 rows x 128B/row (8KB); wave w covers rows pi*64+w*8..+8
  // per-lane source: row lane>>3, chunk (lane&7)^(lane>>3) (inverse swizzle)
  const size_t lsrc = (size_t)(lane >> 3) * K + (size_t)((lane & 7) ^ (lane >> 3)) * 8;
  const _Float16* gA = A + (size_t)brow * K + lsrc;
  const _Float16* gB = B + (size_t)bcol * K + lsrc;

  auto stageA = [&](int buf, int pi, int kt) {
    gload_lds16(gA + (size_t)(pi * 64 + w * 8) * K + kt,
                &sA[buf][(pi * 512 + w * 64) * 8]);
  };
  auto stageB = [&](int buf, int pi, int kt) {
    gload_lds16(gB + (size_t)(pi * 64 + w * 8) * K + kt,
                &sB[buf][(pi * 512 + w * 64) * 8]);
  };

  // swizzled fragment reads: r = g*16 + (lane&15); chunk = (ks*4+(lane>>4)) ^ (lane&7)
  const int rdbase = (lane & 15) * 64;
  const int e0 = rdbase + (((lane >> 4) + 0) ^ (lane & 7)) * 8;   // ks=0
  const int e1 = rdbase + (((lane >> 4) + 4) ^ (lane & 7)) * 8;   // ks=1

  auto ldA = [&](int buf, int mg, half8* a) {
#pragma unroll
    for (int mf = 0; mf < 4; ++mf) {
      const int base = (wr * 8 + mg * 4 + mf) * 1024;
      a[mf * 2 + 0] = *(const half8*)&sA[buf][base + e0];
      a[mf * 2 + 1] = *(const half8*)&sA[buf][base + e1];
    }
  };
  auto ldB = [&](int buf, int ng, half8* b) {
#pragma unroll
    for (int nf = 0; nf < 2; ++nf) {
      const int base = (wc * 4 + ng * 2 + nf) * 1024;
      b[nf * 2 + 0] = *(const half8*)&sB[buf][base + e0];
      b[nf * 2 + 1] = *(const half8*)&sB[buf][base + e1];
    }
  };

  f32x4 acc[8][4] = {};
  const int NT = K / BK;              // 64

  // prologue: A(0),B(0)->buf0, A(1)->buf1; vm(4): tile0 landed, A(1) flying
  stageA(0, 0, 0); stageA(0, 1, 0); stageA(0, 2, 0); stageA(0, 3, 0);
  stageB(0, 0, 0); stageB(0, 1, 0); stageB(0, 2, 0); stageB(0, 3, 0);
  stageA(1, 0, BK); stageA(1, 1, BK); stageA(1, 2, BK); stageA(1, 3, BK);
  WAIT_VM(4);
  BAR();

  for (int t = 0; t < NT; ++t) {
    const int cur = t & 1, nxt = cur ^ 1;
    const int ktB = (t + 1) * BK;
    const int ktA = (t + 2) * BK;
    const bool sb = (t + 1) < NT;
    const bool sa = (t + 2) < NT;
    half8 aL[8], aH[8], bL[4], bH[4];

    // ---- p1: issue all fragment reads in pinned groups; stage B(t+1)
    ldA(cur, 0, aL); ldB(cur, 0, bL);   // group 1: 12 reads
    SCHED_FENCE();
    ldB(cur, 1, bH);                    // group 2: 4 reads
    SCHED_FENCE();
    ldA(cur, 1, aH);                    // group 3: 8 reads
    SCHED_FENCE();
    if (sb) { stageB(nxt, 0, ktB); stageB(nxt, 1, ktB);
              stageB(nxt, 2, ktB); stageB(nxt, 3, ktB); }

    WAIT_LGKM(12); SCHED_FENCE();       // aL,bL retired
    MFMA_Q(aL, bL, 0, 0);
    WAIT_LGKM(8); SCHED_FENCE();        // bH retired
    MFMA_Q(aL, bH, 0, 1);
    WAIT_LGKM(0); SCHED_FENCE();        // aH retired
    BAR();                              // BAR#1: A(cur) readers done everywhere

    // ---- p2: stage A(t+2) into cur under the back-half MFMA burst
    if (sa) { stageA(cur, 0, ktA); stageA(cur, 1, ktA);
              stageA(cur, 2, ktA); stageA(cur, 3, ktA); }
    MFMA_Q(aH, bH, 1, 1);
    MFMA_Q(aH, bL, 1, 0);

    // tile-boundary counted wait: retire A(t+1)+B(t+1), leave A(t+2) in flight
    if (t < NT - 2) { WAIT_VM(4); } else { WAIT_VM(0); }
    BAR();                              // BAR#2: next tile may read buf[nxt]
  }

  // ---- epilogue: C/D 16x16 layout: col = lane&15, row = (lane>>4)*4 + r
  const float sc = is_ptr[0] * ws_ptr[0];
  const int orow = brow + wr * 128;
  const int ocol = bcol + wc * 64;
#pragma unroll
  for (int n = 0; n < 4; ++n) {
    const int col = ocol + n * 16 + (lane & 15);
    const float bv = bias[col];
#pragma unroll
    for (int m = 0; m < 8; ++m) {
#pragma unroll
      for (int r = 0; r < 4; ++r) {
        const int row = orow + m * 16 + (lane >> 4) * 4 + r;
        out[(size_t)row * N + col] = acc[m][n][r] * sc + bv;
      }
    }
  }
}

// ---------------------------------------------------------------------------
extern "C" void kernel_launch(void* const* d_in, const int* in_sizes, int n_in,
                              void* d_out, int out_size, void* d_ws, size_t ws_size,
                              hipStream_t stream) {
  const float* x    = (const float*)d_in[0];
  const float* wgt  = (const float*)d_in[1];
  const float* bias = (const float*)d_in[2];
  const float* is   = (const float*)d_in[3];
  const float* wsc  = (const float*)d_in[4];
  float* out = (float*)d_out;

  const long x_n = in_sizes[0];
  const long w_n = in_sizes[1];
  const int  N   = in_sizes[2];
  const int  K   = (int)(w_n / N);
  const int  M   = (int)(x_n / K);

  _Float16* xq = (_Float16*)d_ws;
  _Float16* wq = xq + x_n;

  cvt_x_kernel<<<2048, 256, 0, stream>>>(x, xq, is, x_n >> 2);
  cvt_w_kernel<<<2048, 256, 0, stream>>>(wgt, wq, w_n >> 2);

  const int nwg = (M / BM) * (N / BN);   // 32 * 64 = 2048, %8 == 0
  gemm256_p2<<<nwg, 512, 0, stream>>>(xq, wq, bias, is, wsc, out, M, N, K);
}